// Round 2
// baseline (9937.687 us; speedup 1.0000x reference)
//
#include <hip/hip_runtime.h>
#include <math.h>

// Problem constants
constexpr int Bn = 64, Sn = 200, Cn = 32, Dn = 256, Vn = 10000, Tn = 1000;
constexpr int G3 = 3 * Dn; // 768

// ---------------------------------------------------------------------------
// x[b,s,d] = sum_c emb[seqs[b,s,c]][d]
__global__ __launch_bounds__(256) void k_embed_sum(const int* __restrict__ seqs,
    const float* __restrict__ emb, float* __restrict__ x) {
  const int bs = blockIdx.x;
  const int d = threadIdx.x;
  const int* row = seqs + (size_t)bs * Cn;
  float acc = 0.f;
#pragma unroll
  for (int c = 0; c < Cn; ++c) acc += emb[(size_t)row[c] * Dn + d];
  x[(size_t)bs * Dn + d] = acc;
}

// ---------------------------------------------------------------------------
// C[M,N] = A[M,K] @ B[N,K]^T + bias[N]   (row-major, K multiple of 16)
__global__ __launch_bounds__(256) void k_gemm_abt(const float* __restrict__ A,
    const float* __restrict__ Bm, const float* __restrict__ bias,
    float* __restrict__ Cm, int M, int N, int K) {
  __shared__ float As[16][132];
  __shared__ float Bs[16][132];
  const int m0 = blockIdx.x * 128, n0 = blockIdx.y * 128;
  const int tid = threadIdx.x;
  const int lk = tid & 15, lm = tid >> 4;
  const int tx = tid & 15, ty = tid >> 4;
  float acc[8][8] = {};
  for (int k0 = 0; k0 < K; k0 += 16) {
#pragma unroll
    for (int i = 0; i < 8; ++i) {
      int m = lm + i * 16;
      int gm = m0 + m, gn = n0 + m;
      As[lk][m] = (gm < M) ? A[(size_t)gm * K + k0 + lk] : 0.f;
      Bs[lk][m] = (gn < N) ? Bm[(size_t)gn * K + k0 + lk] : 0.f;
    }
    __syncthreads();
#pragma unroll
    for (int k = 0; k < 16; ++k) {
      float a[8], bb[8];
#pragma unroll
      for (int i = 0; i < 8; ++i) a[i] = As[k][ty * 8 + i];
#pragma unroll
      for (int j = 0; j < 8; ++j) bb[j] = Bs[k][tx * 8 + j];
#pragma unroll
      for (int i = 0; i < 8; ++i)
#pragma unroll
        for (int j = 0; j < 8; ++j) acc[i][j] += a[i] * bb[j];
    }
    __syncthreads();
  }
#pragma unroll
  for (int i = 0; i < 8; ++i) {
    int gm = m0 + ty * 8 + i;
    if (gm >= M) continue;
#pragma unroll
    for (int j = 0; j < 8; ++j) {
      int gn = n0 + tx * 8 + j;
      if (gn < N) Cm[(size_t)gm * N + gn] = acc[i][j] + bias[gn];
    }
  }
}

// ---------------------------------------------------------------------------
// GRU scan for one batch element per block. 512 threads: d = tid&255 owns the
// gate triple (d, D+d, 2D+d); half = tid>>8 splits K range for latency hiding.
__global__ __launch_bounds__(512) void k_gru(const float* __restrict__ xp,
    const float* __restrict__ Whh, const float* __restrict__ bhh,
    float* __restrict__ out) {
  const int b = blockIdx.x;
  const int tid = threadIdx.x;
  const int d = tid & 255;
  const int half = tid >> 8;
  __shared__ __align__(16) float hs[Dn];
  __shared__ float red[3][Dn];
  if (tid < Dn) hs[tid] = 0.f;
  __syncthreads();
  const float4* wr = (const float4*)(Whh + (size_t)d * Dn) + half * 32;
  const float4* wz = (const float4*)(Whh + (size_t)(Dn + d) * Dn) + half * 32;
  const float4* wn = (const float4*)(Whh + (size_t)(2 * Dn + d) * Dn) + half * 32;
  const float4* h4p = (const float4*)hs + half * 32;
  const float* xpb = xp + (size_t)b * Sn * G3;
  const float br = bhh[d], bz = bhh[Dn + d], bn = bhh[2 * Dn + d];
  for (int t = 0; t < Sn; ++t) {
    float ar = 0.f, az = 0.f, an = 0.f;
#pragma unroll 4
    for (int k = 0; k < 32; ++k) {
      float4 h4 = h4p[k];
      float4 w;
      w = wr[k]; ar += h4.x * w.x; ar += h4.y * w.y; ar += h4.z * w.z; ar += h4.w * w.w;
      w = wz[k]; az += h4.x * w.x; az += h4.y * w.y; az += h4.z * w.z; az += h4.w * w.w;
      w = wn[k]; an += h4.x * w.x; an += h4.y * w.y; an += h4.z * w.z; an += h4.w * w.w;
    }
    if (half) { red[0][d] = ar; red[1][d] = az; red[2][d] = an; }
    __syncthreads();
    if (!half) {
      const float* xr = xpb + (size_t)t * G3;
      float hpr = ar + red[0][d] + br;
      float hpz = az + red[1][d] + bz;
      float hpn = an + red[2][d] + bn;
      float r = 1.f / (1.f + __expf(-(xr[d] + hpr)));
      float z = 1.f / (1.f + __expf(-(xr[Dn + d] + hpz)));
      float n = tanhf(xr[2 * Dn + d] + r * hpn);
      float h = (1.f - z) * n + z * hs[d];
      hs[d] = h;
      out[((size_t)b * Sn + t) * Dn + d] = h;
    }
    __syncthreads();
  }
}

// ---------------------------------------------------------------------------
// ekproj[b,f] = w1_b[f] + sum_k x[b,0,k] * w1_W[f,k]   (first D cols of w1_W)
__global__ __launch_bounds__(64) void k_ekproj(const float* __restrict__ x,
    const float* __restrict__ w1W, const float* __restrict__ w1b,
    float* __restrict__ ekproj) {
  const int b = blockIdx.x, f = threadIdx.x;
  const float* xr = x + (size_t)b * Sn * Dn;
  const float* wr = w1W + (size_t)f * (2 * Dn);
  float acc = w1b[f];
  for (int k = 0; k < Dn; ++k) acc += xr[k] * wr[k];
  ekproj[b * 64 + f] = acc;
}

// ---------------------------------------------------------------------------
// Fused location attention + blend. One block per batch, loops s=1..S-1.
// aligned[b,0,:]=x[b,0,:]; aligned[b,s,:]=e_k*a0 + w_prev[b,s-1]*a1.
__global__ __launch_bounds__(256) void k_attn(const float* __restrict__ x,
    const float* __restrict__ wprev, const float* __restrict__ ekproj,
    const float* __restrict__ w1W, const float* __restrict__ w2W,
    const float* __restrict__ w2b, float* __restrict__ aligned) {
  const int b = blockIdx.x, tid = threadIdx.x;
  __shared__ float ek[Dn], wp[Dn], eks[64], t1[64], red[256], lg[2], a01[2];
  ek[tid] = x[(size_t)b * Sn * Dn + tid];
  if (tid < 64) eks[tid] = ekproj[b * 64 + tid];
  aligned[(size_t)b * Sn * Dn + tid] = ek[tid];
  const int f = tid & 63, q = tid >> 6;
  const float* w1r = w1W + (size_t)f * (2 * Dn) + Dn; // second-half row f
  __syncthreads();
  for (int s = 1; s < Sn; ++s) {
    wp[tid] = wprev[((size_t)b * Sn + (s - 1)) * Dn + tid];
    __syncthreads();
    float p = 0.f;
#pragma unroll 4
    for (int k = q * 64; k < q * 64 + 64; ++k) p += wp[k] * w1r[k];
    red[tid] = p;
    __syncthreads();
    if (tid < 64)
      t1[tid] = tanhf(eks[tid] + red[tid] + red[64 + tid] + red[128 + tid] + red[192 + tid]);
    __syncthreads();
    if (tid < 2) {
      float acc = w2b[tid];
#pragma unroll
      for (int j = 0; j < 64; ++j) acc += t1[j] * w2W[tid * 64 + j];
      lg[tid] = acc;
    }
    __syncthreads();
    if (tid == 0) {
      float m = fmaxf(lg[0], lg[1]);
      float e0 = __expf(lg[0] - m), e1 = __expf(lg[1] - m);
      float inv = 1.f / (e0 + e1);
      a01[0] = e0 * inv; a01[1] = e1 * inv;
    }
    __syncthreads();
    aligned[((size_t)b * Sn + s) * Dn + tid] = ek[tid] * a01[0] + wp[tid] * a01[1];
    __syncthreads();
  }
}

// ---------------------------------------------------------------------------
// cumprod(1-betas) -> per-batch sqrt(alpha), sqrt(1-alpha), time_scale gather
__global__ __launch_bounds__(256) void k_cumsetup(const float* __restrict__ betas,
    const int* __restrict__ difft, const float* __restrict__ tscale,
    float* __restrict__ sa, float* __restrict__ sb, float* __restrict__ tsv) {
  __shared__ float bl[Tn];
  const int tid = threadIdx.x;
  for (int i = tid; i < Tn; i += 256) bl[i] = betas[i];
  __syncthreads();
  if (tid == 0) {
    float p = 1.f;
    for (int t = 0; t < Tn; ++t) { p *= (1.f - bl[t]); bl[t] = p; }
  }
  __syncthreads();
  if (tid < Bn) {
    int tb = difft[tid];
    float a = bl[tb];
    sa[tid] = sqrtf(a);
    sb[tid] = sqrtf(1.f - a);
    tsv[tid] = tscale[tb];
  }
}

// ---------------------------------------------------------------------------
// x_noisy = aligned*sqrt(alpha[b]) + noise*sqrt(1-alpha[b])
__global__ __launch_bounds__(256) void k_noisy(const float* __restrict__ aligned,
    const float* __restrict__ noise, const float* __restrict__ sa,
    const float* __restrict__ sb, float* __restrict__ xn) {
  const size_t NT = (size_t)Bn * Sn * Dn;
  const size_t stride = (size_t)gridDim.x * blockDim.x;
  for (size_t i = (size_t)blockIdx.x * blockDim.x + threadIdx.x; i < NT; i += stride) {
    int b = (int)(i / (Sn * Dn));
    xn[i] = aligned[i] * sa[b] + noise[i] * sb[b];
  }
}

// ---------------------------------------------------------------------------
// pn[b,c,d] = ts[b] * sum_s Wd[c,s]*xn[b,s,d];  genx = aligned + noise - pn
__global__ __launch_bounds__(256) void k_diff(const float* __restrict__ Wd,
    const float* __restrict__ Xn, const float* __restrict__ tsv,
    const float* __restrict__ aligned, const float* __restrict__ noise,
    float* __restrict__ pn, float* __restrict__ genx) {
  const int bz = blockIdx.z;
  const float* Bm = Xn + (size_t)bz * Sn * Dn;
  __shared__ float As[16][65];
  __shared__ float Bs[16][65];
  const int m0 = blockIdx.x * 64, n0 = blockIdx.y * 64;
  const int tid = threadIdx.x;
  const int lk = tid & 15, lm = tid >> 4;
  const int ln = tid & 63, lq = tid >> 6;
  const int tx = tid & 15, ty = tid >> 4;
  float acc[4][4] = {};
  for (int k0 = 0; k0 < Sn; k0 += 16) {
#pragma unroll
    for (int i = 0; i < 4; ++i) {
      int m = lm + i * 16;
      As[lk][m] = (m0 + m < Sn && k0 + lk < Sn) ? Wd[(size_t)(m0 + m) * Sn + k0 + lk] : 0.f;
    }
#pragma unroll
    for (int i = 0; i < 4; ++i) {
      int k = lq + i * 4;
      Bs[k][ln] = (k0 + k < Sn) ? Bm[(size_t)(k0 + k) * Dn + n0 + ln] : 0.f;
    }
    __syncthreads();
#pragma unroll
    for (int k = 0; k < 16; ++k) {
      float a[4], bb[4];
#pragma unroll
      for (int i = 0; i < 4; ++i) a[i] = As[k][ty * 4 + i];
#pragma unroll
      for (int j = 0; j < 4; ++j) bb[j] = Bs[k][tx * 4 + j];
#pragma unroll
      for (int i = 0; i < 4; ++i)
#pragma unroll
        for (int j = 0; j < 4; ++j) acc[i][j] += a[i] * bb[j];
    }
    __syncthreads();
  }
  const float ts = tsv[bz];
#pragma unroll
  for (int i = 0; i < 4; ++i) {
    int c = m0 + ty * 4 + i;
    if (c >= Sn) continue;
#pragma unroll
    for (int j = 0; j < 4; ++j) {
      int dd = n0 + tx * 4 + j;
      size_t idx = ((size_t)bz * Sn + c) * Dn + dd;
      float val = acc[i][j] * ts;
      pn[idx] = val;
      genx[idx] = aligned[idx] + noise[idx] - val;
    }
  }
}

// ---------------------------------------------------------------------------
// attention pool: att=softmax(rnn@wl+b over s); feat=sum att*rnn; pred=feat@outW^T+b
__global__ __launch_bounds__(256) void k_pool(const float* __restrict__ rnn,
    const float* __restrict__ wlW, const float* __restrict__ wlb,
    const float* __restrict__ outW, const float* __restrict__ outb,
    float* __restrict__ out2) {
  const int b = blockIdx.x, tid = threadIdx.x;
  __shared__ float wl[Dn], att[256], red[256], feat[Dn];
  wl[tid] = wlW[tid];
  __syncthreads();
  float wv = -1e30f;
  if (tid < Sn) {
    const float* r = rnn + ((size_t)b * Sn + tid) * Dn;
    float a = wlb[0];
    for (int k = 0; k < Dn; ++k) a += r[k] * wl[k];
    wv = a;
  }
  red[tid] = wv;
  __syncthreads();
  for (int off = 128; off > 0; off >>= 1) {
    if (tid < off) red[tid] = fmaxf(red[tid], red[tid + off]);
    __syncthreads();
  }
  const float m = red[0];
  __syncthreads();
  float e = (tid < Sn) ? __expf(wv - m) : 0.f;
  red[tid] = e;
  __syncthreads();
  for (int off = 128; off > 0; off >>= 1) {
    if (tid < off) red[tid] += red[tid + off];
    __syncthreads();
  }
  const float inv = 1.f / red[0];
  att[tid] = e * inv;
  __syncthreads();
  const float* rb = rnn + (size_t)b * Sn * Dn;
  float a = 0.f;
  for (int s = 0; s < Sn; ++s) a += rb[(size_t)s * Dn + tid] * att[s];
  feat[tid] = a;
  __syncthreads();
  if (tid < 2) {
    float acc = outb[tid];
    for (int k = 0; k < Dn; ++k) acc += feat[k] * outW[tid * Dn + k];
    out2[b * 2 + tid] = acc;
  }
}

// ---------------------------------------------------------------------------
extern "C" void kernel_launch(void* const* d_in, const int* in_sizes, int n_in,
                              void* d_out, int out_size, void* d_ws, size_t ws_size,
                              hipStream_t stream) {
  const int*   seqs   = (const int*)  d_in[0];
  const int*   difft  = (const int*)  d_in[5];
  const float* emb    = (const float*)d_in[6];
  const float* Wih    = (const float*)d_in[7];
  const float* Whh    = (const float*)d_in[8];
  const float* bih    = (const float*)d_in[9];
  const float* bhh    = (const float*)d_in[10];
  const float* whkW   = (const float*)d_in[11];
  const float* whkb   = (const float*)d_in[12];
  const float* w1W    = (const float*)d_in[13];
  const float* w1b    = (const float*)d_in[14];
  const float* w2W    = (const float*)d_in[15];
  const float* w2b    = (const float*)d_in[16];
  const float* wlW    = (const float*)d_in[17];
  const float* wlb    = (const float*)d_in[18];
  const float* outW   = (const float*)d_in[19];
  const float* outb   = (const float*)d_in[20];
  const float* betas  = (const float*)d_in[21];
  const float* Wd     = (const float*)d_in[22];
  const float* tscale = (const float*)d_in[23];
  const float* noise  = (const float*)d_in[24];

  float* ws = (float*)d_ws;
  const size_t NX  = (size_t)Bn * Sn * Dn;  // 3,276,800
  const size_t NXP = (size_t)Bn * Sn * G3;  // 9,830,400
  // Layout (total = 3*NX + NXP + 4*64 + B*64 floats ~= 78.7 MB):
  //   [0, NX)                  x          (embed output; read until step 8)
  //   [NX, NX+NXP)             xp         (GRU input; dead between step 3 and 10)
  //       xp[0, NX)            x_noisy    (written step 8, read step 9 — before step 10 re-writes xp)
  //       xp[NX, 2*NX)         aligned    (written step 6, read steps 8/9 — before step 10)
  //   [NX+NXP, 2*NX+NXP)       rnn
  //   [2*NX+NXP, 3*NX+NXP)     wprev -> gen_x -> gen_rnn
  //   tail: sa/sb/tsv/ekproj
  float* x       = ws;
  float* xp      = ws + NX;
  float* xnoisy  = xp;            // aliases xp[0, NX)
  float* aligned = xp + NX;       // aliases xp[NX, 2*NX)
  float* rnn     = ws + NX + NXP;
  float* wprev   = ws + 2 * NX + NXP;
  float* sa      = ws + 3 * NX + NXP;
  float* sb      = sa + 64;
  float* tsv     = sb + 64;
  float* ekproj  = tsv + 64;      // B*64 floats

  float* out       = (float*)d_out;
  float* pred      = out;
  float* gpred     = out + 128;
  float* pn        = out + 256;
  float* out_noise = out + 256 + NX;

  // 1. embedding sum
  k_embed_sum<<<dim3(Bn * Sn), dim3(Dn), 0, stream>>>(seqs, emb, x);
  // 2. xp = x @ Wih^T + bih
  k_gemm_abt<<<dim3(100, 6), dim3(256), 0, stream>>>(x, Wih, bih, xp, Bn * Sn, G3, Dn);
  // 3. rnn = GRU(xp)
  k_gru<<<dim3(Bn), dim3(512), 0, stream>>>(xp, Whh, bhh, rnn);
  // 4. w_prev(full S) = rnn @ whk^T + b
  k_gemm_abt<<<dim3(100, 2), dim3(256), 0, stream>>>(rnn, whkW, whkb, wprev, Bn * Sn, Dn, Dn);
  // 5. e_k projection through first half of w1
  k_ekproj<<<dim3(Bn), dim3(64), 0, stream>>>(x, w1W, w1b, ekproj);
  // 6. fused attention + blend -> aligned
  k_attn<<<dim3(Bn), dim3(256), 0, stream>>>(x, wprev, ekproj, w1W, w2W, w2b, aligned);
  // 7. diffusion scalars
  k_cumsetup<<<dim3(1), dim3(256), 0, stream>>>(betas, difft, tscale, sa, sb, tsv);
  // 8. x_noisy (into dead xp region; x itself no longer needed after this point)
  k_noisy<<<dim3(2048), dim3(256), 0, stream>>>(aligned, noise, sa, sb, xnoisy);
  // 9. predicted_noise (-> d_out) and gen_x (overwrites wprev)
  k_diff<<<dim3(4, 4, Bn), dim3(256), 0, stream>>>(Wd, xnoisy, tsv, aligned, noise, pn, wprev);
  // 10. gen xp = gen_x @ Wih^T + bih  (re-writes xp region; x_noisy/aligned now dead)
  k_gemm_abt<<<dim3(100, 6), dim3(256), 0, stream>>>(wprev, Wih, bih, xp, Bn * Sn, G3, Dn);
  // 11. gen_rnn = GRU (overwrites gen_x slot)
  k_gru<<<dim3(Bn), dim3(512), 0, stream>>>(xp, Whh, bhh, wprev);
  // 12. pools
  k_pool<<<dim3(Bn), dim3(256), 0, stream>>>(rnn, wlW, wlb, outW, outb, pred);
  k_pool<<<dim3(Bn), dim3(256), 0, stream>>>(wprev, wlW, wlb, outW, outb, gpred);
  // 13. pass through normal_noise
  hipMemcpyAsync(out_noise, noise, NX * sizeof(float), hipMemcpyDeviceToDevice, stream);
}

// Round 5
// 1795.547 us; speedup vs baseline: 5.5346x; 5.5346x over previous
//
#include <hip/hip_runtime.h>
#include <math.h>

// Problem constants
constexpr int Bn = 64, Sn = 200, Cn = 32, Dn = 256, Vn = 10000, Tn = 1000;
constexpr int G3 = 3 * Dn; // 768

typedef __fp16 h2_t __attribute__((ext_vector_type(2)));

static __device__ __forceinline__ h2_t as_h2(uint v) {
  union { uint u; h2_t h; } c; c.u = v; return c.h;
}
static __device__ __forceinline__ uint as_u32(h2_t h) {
  union { h2_t h; uint u; } c; c.h = h; return c.u;
}

// ---------------------------------------------------------------------------
// Whh f32 -> packed f16 pairs (u32), pair i = (w[2i], w[2i+1])
__global__ __launch_bounds__(256) void k_w2f16(const float* __restrict__ w,
    uint* __restrict__ o, int npairs) {
  int i = blockIdx.x * 256 + threadIdx.x;
  if (i < npairs) {
    h2_t pk = __builtin_amdgcn_cvt_pkrtz(w[2 * i], w[2 * i + 1]);
    o[i] = as_u32(pk);
  }
}

// ---------------------------------------------------------------------------
// x[b,s,d] = sum_c emb[seqs[b,s,c]][d]
__global__ __launch_bounds__(256) void k_embed_sum(const int* __restrict__ seqs,
    const float* __restrict__ emb, float* __restrict__ x) {
  const int bs = blockIdx.x;
  const int d = threadIdx.x;
  const int* row = seqs + (size_t)bs * Cn;
  float acc = 0.f;
#pragma unroll
  for (int c = 0; c < Cn; ++c) acc += emb[(size_t)row[c] * Dn + d];
  x[(size_t)bs * Dn + d] = acc;
}

// ---------------------------------------------------------------------------
// C[M,N] = A[M,K] @ B[N,K]^T + bias[N]   (row-major, K multiple of 16)
__global__ __launch_bounds__(256) void k_gemm_abt(const float* __restrict__ A,
    const float* __restrict__ Bm, const float* __restrict__ bias,
    float* __restrict__ Cm, int M, int N, int K) {
  __shared__ float As[16][132];
  __shared__ float Bs[16][132];
  const int m0 = blockIdx.x * 128, n0 = blockIdx.y * 128;
  const int tid = threadIdx.x;
  const int lk = tid & 15, lm = tid >> 4;
  const int tx = tid & 15, ty = tid >> 4;
  float acc[8][8] = {};
  for (int k0 = 0; k0 < K; k0 += 16) {
#pragma unroll
    for (int i = 0; i < 8; ++i) {
      int m = lm + i * 16;
      int gm = m0 + m, gn = n0 + m;
      As[lk][m] = (gm < M) ? A[(size_t)gm * K + k0 + lk] : 0.f;
      Bs[lk][m] = (gn < N) ? Bm[(size_t)gn * K + k0 + lk] : 0.f;
    }
    __syncthreads();
#pragma unroll
    for (int k = 0; k < 16; ++k) {
      float a[8], bb[8];
#pragma unroll
      for (int i = 0; i < 8; ++i) a[i] = As[k][ty * 8 + i];
#pragma unroll
      for (int j = 0; j < 8; ++j) bb[j] = Bs[k][tx * 8 + j];
#pragma unroll
      for (int i = 0; i < 8; ++i)
#pragma unroll
        for (int j = 0; j < 8; ++j) acc[i][j] += a[i] * bb[j];
    }
    __syncthreads();
  }
#pragma unroll
  for (int i = 0; i < 8; ++i) {
    int gm = m0 + ty * 8 + i;
    if (gm >= M) continue;
#pragma unroll
    for (int j = 0; j < 8; ++j) {
      int gn = n0 + tx * 8 + j;
      if (gn < N) Cm[(size_t)gm * N + gn] = acc[i][j] + bias[gn];
    }
  }
}

// ---------------------------------------------------------------------------
// GRU with register-resident f16 Whh. One block per batch element.
// 512 threads: q = tid&7 owns k in [32q, 32q+32) (16 u32 of f16 pairs);
// g = tid>>3 owns gate-rows 12g..12g+11. Per step: 192 fdot2 per thread,
// 3-level shfl reduce over q, h exchanged as f16 pairs via 512B of LDS.
__global__ __launch_bounds__(512) void k_gru_reg(const float* __restrict__ xp,
    const uint* __restrict__ Wh, const float* __restrict__ bhh,
    float* __restrict__ out) {
  const int b = blockIdx.x;
  const int tid = threadIdx.x;
  const int q = tid & 7;
  const int g = tid >> 3;
  __shared__ uint h2s[128];     // h[256] as f16 pairs
  __shared__ float red[768];    // Whh @ h pre-activations

  // one-time: weights into VGPRs (12 rows x 16 u32 = 192 regs)
  uint w[12][16];
#pragma unroll
  for (int j = 0; j < 12; ++j) {
    const uint* src = Wh + (size_t)(12 * g + j) * 128 + 16 * q;
#pragma unroll
    for (int i = 0; i < 16; i += 4) {
      uint4 v = *reinterpret_cast<const uint4*>(src + i);
      w[j][i] = v.x; w[j][i + 1] = v.y; w[j][i + 2] = v.z; w[j][i + 3] = v.w;
    }
  }
  const int d = tid;
  float b_r = 0.f, b_z = 0.f, b_n = 0.f, h_old = 0.f;
  float x_r = 0.f, x_z = 0.f, x_n = 0.f;
  const float* xpb = xp + (size_t)b * Sn * G3;
  if (tid < 256) {
    b_r = bhh[d]; b_z = bhh[256 + d]; b_n = bhh[512 + d];
    x_r = xpb[d]; x_z = xpb[256 + d]; x_n = xpb[512 + d];
  }
  if (tid < 128) h2s[tid] = 0u;
  __syncthreads();

  for (int t = 0; t < Sn; ++t) {
    // read own h octant (16 u32 = 32 f16)
    uint hr[16];
    {
      const uint* hp = h2s + 16 * q;
#pragma unroll
      for (int i = 0; i < 16; i += 4) {
        uint4 v = *reinterpret_cast<const uint4*>(hp + i);
        hr[i] = v.x; hr[i + 1] = v.y; hr[i + 2] = v.z; hr[i + 3] = v.w;
      }
    }
    float acc[12];
#pragma unroll
    for (int j = 0; j < 12; ++j) acc[j] = 0.f;
#pragma unroll
    for (int i = 0; i < 16; ++i) {
      h2_t hh = as_h2(hr[i]);
#pragma unroll
      for (int j = 0; j < 12; ++j)
        acc[j] = __builtin_amdgcn_fdot2(as_h2(w[j][i]), hh, acc[j], false);
    }
#pragma unroll
    for (int j = 0; j < 12; ++j) {
      float s = acc[j];
      s += __shfl_xor(s, 1);
      s += __shfl_xor(s, 2);
      s += __shfl_xor(s, 4);
      if (q == 0) red[12 * g + j] = s;
    }
    __syncthreads();
    if (tid < 256) {
      float rv = 1.f / (1.f + __expf(-(x_r + red[d] + b_r)));
      float zv = 1.f / (1.f + __expf(-(x_z + red[256 + d] + b_z)));
      float nv = tanhf(x_n + rv * (red[512 + d] + b_n));
      float h = (1.f - zv) * nv + zv * h_old;
      h_old = h;
      out[((size_t)b * Sn + t) * Dn + d] = h;
      if (t + 1 < Sn) {  // prefetch next step's xp triple
        const float* xr = xpb + (size_t)(t + 1) * G3;
        x_r = xr[d]; x_z = xr[256 + d]; x_n = xr[512 + d];
      }
      float hp = __shfl_xor(h, 1);
      if ((d & 1) == 0) h2s[d >> 1] = as_u32(__builtin_amdgcn_cvt_pkrtz(h, hp));
    }
    __syncthreads();
  }
}

// ---------------------------------------------------------------------------
// Parallel location-attention + blend. softmax is over the 2-class axis, so
// every (b,s) is independent. Grid (B, 7): block stages w1 in dynamic LDS
// once, then handles 29 s-values. aligned[b,0,:]=x[b,0,:].
__global__ __launch_bounds__(256) void k_attn_par(const float* __restrict__ x,
    const float* __restrict__ wprev, const float* __restrict__ w1W,
    const float* __restrict__ w1b, const float* __restrict__ w2W,
    const float* __restrict__ w2b, float* __restrict__ aligned) {
  extern __shared__ float sm[];
  float* w1s = sm;                  // 64 x 513 (pad: conflict-free)
  float* ek  = w1s + 64 * 513;      // 256
  float* wp  = ek + 256;            // 256
  float* eks = wp + 256;            // 64
  float* t1  = eks + 64;            // 64
  float* a01 = t1 + 64;             // 2
  const int b = blockIdx.x, cy = blockIdx.y, tid = threadIdx.x;
  for (int idx = tid; idx < 64 * 512; idx += 256) {
    int f = idx >> 9, c = idx & 511;
    w1s[f * 513 + c] = w1W[idx];
  }
  ek[tid] = x[(size_t)b * Sn * Dn + tid];
  __syncthreads();
  const int f = tid >> 2, kq = tid & 3;
  {
    float p = 0.f;
    const float* wr = w1s + f * 513;
#pragma unroll 8
    for (int j = 0; j < 64; ++j) {
      int k = 64 * kq + ((j + 16 * kq) & 63);  // stagger: spread banks
      p += ek[k] * wr[k];
    }
    p += __shfl_xor(p, 1);
    p += __shfl_xor(p, 2);
    if (kq == 0) eks[f] = p + w1b[f];
  }
  if (cy == 0) aligned[(size_t)b * Sn * Dn + tid] = ek[tid];
  __syncthreads();
  const int s0 = 1 + cy * 29;
  const int s1 = (s0 + 29 < Sn) ? s0 + 29 : Sn;
  for (int s = s0; s < s1; ++s) {
    wp[tid] = wprev[((size_t)b * Sn + (s - 1)) * Dn + tid];
    __syncthreads();
    float p = 0.f;
    const float* wr = w1s + f * 513 + 256;
#pragma unroll 8
    for (int j = 0; j < 64; ++j) {
      int k = 64 * kq + ((j + 16 * kq) & 63);
      p += wp[k] * wr[k];
    }
    p += __shfl_xor(p, 1);
    p += __shfl_xor(p, 2);
    if (kq == 0) t1[f] = tanhf(eks[f] + p);
    __syncthreads();
    if (tid == 0) {
      float l0 = w2b[0], l1 = w2b[1];
#pragma unroll
      for (int j = 0; j < 64; ++j) { l0 += t1[j] * w2W[j]; l1 += t1[j] * w2W[64 + j]; }
      float m = fmaxf(l0, l1);
      float e0 = __expf(l0 - m), e1 = __expf(l1 - m);
      float inv = 1.f / (e0 + e1);
      a01[0] = e0 * inv; a01[1] = e1 * inv;
    }
    __syncthreads();
    aligned[((size_t)b * Sn + s) * Dn + tid] = ek[tid] * a01[0] + wp[tid] * a01[1];
    __syncthreads();
  }
}

// ---------------------------------------------------------------------------
// cumprod(1-betas) -> per-batch sqrt(alpha), sqrt(1-alpha), time_scale gather
__global__ __launch_bounds__(256) void k_cumsetup(const float* __restrict__ betas,
    const int* __restrict__ difft, const float* __restrict__ tscale,
    float* __restrict__ sa, float* __restrict__ sb, float* __restrict__ tsv) {
  __shared__ float bl[Tn];
  const int tid = threadIdx.x;
  for (int i = tid; i < Tn; i += 256) bl[i] = betas[i];
  __syncthreads();
  if (tid == 0) {
    float p = 1.f;
    for (int t = 0; t < Tn; ++t) { p *= (1.f - bl[t]); bl[t] = p; }
  }
  __syncthreads();
  if (tid < Bn) {
    int tb = difft[tid];
    float a = bl[tb];
    sa[tid] = sqrtf(a);
    sb[tid] = sqrtf(1.f - a);
    tsv[tid] = tscale[tb];
  }
}

// ---------------------------------------------------------------------------
// x_noisy = aligned*sqrt(alpha[b]) + noise*sqrt(1-alpha[b])
__global__ __launch_bounds__(256) void k_noisy(const float* __restrict__ aligned,
    const float* __restrict__ noise, const float* __restrict__ sa,
    const float* __restrict__ sb, float* __restrict__ xn) {
  const size_t NT = (size_t)Bn * Sn * Dn;
  const size_t stride = (size_t)gridDim.x * blockDim.x;
  for (size_t i = (size_t)blockIdx.x * blockDim.x + threadIdx.x; i < NT; i += stride) {
    int b = (int)(i / (Sn * Dn));
    xn[i] = aligned[i] * sa[b] + noise[i] * sb[b];
  }
}

// ---------------------------------------------------------------------------
// pn[b,c,d] = ts[b] * sum_s Wd[c,s]*xn[b,s,d];  genx = aligned + noise - pn
__global__ __launch_bounds__(256) void k_diff(const float* __restrict__ Wd,
    const float* __restrict__ Xn, const float* __restrict__ tsv,
    const float* __restrict__ aligned, const float* __restrict__ noise,
    float* __restrict__ pn, float* __restrict__ genx) {
  const int bz = blockIdx.z;
  const float* Bm = Xn + (size_t)bz * Sn * Dn;
  __shared__ float As[16][65];
  __shared__ float Bs[16][65];
  const int m0 = blockIdx.x * 64, n0 = blockIdx.y * 64;
  const int tid = threadIdx.x;
  const int lk = tid & 15, lm = tid >> 4;
  const int ln = tid & 63, lq = tid >> 6;
  const int tx = tid & 15, ty = tid >> 4;
  float acc[4][4] = {};
  for (int k0 = 0; k0 < Sn; k0 += 16) {
#pragma unroll
    for (int i = 0; i < 4; ++i) {
      int m = lm + i * 16;
      As[lk][m] = (m0 + m < Sn && k0 + lk < Sn) ? Wd[(size_t)(m0 + m) * Sn + k0 + lk] : 0.f;
    }
#pragma unroll
    for (int i = 0; i < 4; ++i) {
      int k = lq + i * 4;
      Bs[k][ln] = (k0 + k < Sn) ? Bm[(size_t)(k0 + k) * Dn + n0 + ln] : 0.f;
    }
    __syncthreads();
#pragma unroll
    for (int k = 0; k < 16; ++k) {
      float a[4], bb[4];
#pragma unroll
      for (int i = 0; i < 4; ++i) a[i] = As[k][ty * 4 + i];
#pragma unroll
      for (int j = 0; j < 4; ++j) bb[j] = Bs[k][tx * 4 + j];
#pragma unroll
      for (int i = 0; i < 4; ++i)
#pragma unroll
        for (int j = 0; j < 4; ++j) acc[i][j] += a[i] * bb[j];
    }
    __syncthreads();
  }
  const float ts = tsv[bz];
#pragma unroll
  for (int i = 0; i < 4; ++i) {
    int c = m0 + ty * 4 + i;
    if (c >= Sn) continue;
#pragma unroll
    for (int j = 0; j < 4; ++j) {
      int dd = n0 + tx * 4 + j;
      size_t idx = ((size_t)bz * Sn + c) * Dn + dd;
      float val = acc[i][j] * ts;
      pn[idx] = val;
      genx[idx] = aligned[idx] + noise[idx] - val;
    }
  }
}

// ---------------------------------------------------------------------------
// attention pool: att=softmax(rnn@wl+b over s); feat=sum att*rnn; pred=feat@outW^T+b
__global__ __launch_bounds__(256) void k_pool(const float* __restrict__ rnn,
    const float* __restrict__ wlW, const float* __restrict__ wlb,
    const float* __restrict__ outW, const float* __restrict__ outb,
    float* __restrict__ out2) {
  const int b = blockIdx.x, tid = threadIdx.x;
  __shared__ float wl[Dn], att[256], red[256], feat[Dn];
  wl[tid] = wlW[tid];
  __syncthreads();
  float wv = -1e30f;
  if (tid < Sn) {
    const float* r = rnn + ((size_t)b * Sn + tid) * Dn;
    float a = wlb[0];
    for (int k = 0; k < Dn; ++k) a += r[k] * wl[k];
    wv = a;
  }
  red[tid] = wv;
  __syncthreads();
  for (int off = 128; off > 0; off >>= 1) {
    if (tid < off) red[tid] = fmaxf(red[tid], red[tid + off]);
    __syncthreads();
  }
  const float m = red[0];
  __syncthreads();
  float e = (tid < Sn) ? __expf(wv - m) : 0.f;
  red[tid] = e;
  __syncthreads();
  for (int off = 128; off > 0; off >>= 1) {
    if (tid < off) red[tid] += red[tid + off];
    __syncthreads();
  }
  const float inv = 1.f / red[0];
  att[tid] = e * inv;
  __syncthreads();
  const float* rb = rnn + (size_t)b * Sn * Dn;
  float a = 0.f;
  for (int s = 0; s < Sn; ++s) a += rb[(size_t)s * Dn + tid] * att[s];
  feat[tid] = a;
  __syncthreads();
  if (tid < 2) {
    float acc = outb[tid];
    for (int k = 0; k < Dn; ++k) acc += feat[k] * outW[tid * Dn + k];
    out2[b * 2 + tid] = acc;
  }
}

// ---------------------------------------------------------------------------
extern "C" void kernel_launch(void* const* d_in, const int* in_sizes, int n_in,
                              void* d_out, int out_size, void* d_ws, size_t ws_size,
                              hipStream_t stream) {
  const int*   seqs   = (const int*)  d_in[0];
  const int*   difft  = (const int*)  d_in[5];
  const float* emb    = (const float*)d_in[6];
  const float* Wih    = (const float*)d_in[7];
  const float* Whh    = (const float*)d_in[8];
  const float* bih    = (const float*)d_in[9];
  const float* bhh    = (const float*)d_in[10];
  const float* whkW   = (const float*)d_in[11];
  const float* whkb   = (const float*)d_in[12];
  const float* w1W    = (const float*)d_in[13];
  const float* w1b    = (const float*)d_in[14];
  const float* w2W    = (const float*)d_in[15];
  const float* w2b    = (const float*)d_in[16];
  const float* wlW    = (const float*)d_in[17];
  const float* wlb    = (const float*)d_in[18];
  const float* outW   = (const float*)d_in[19];
  const float* outb   = (const float*)d_in[20];
  const float* betas  = (const float*)d_in[21];
  const float* Wd     = (const float*)d_in[22];
  const float* tscale = (const float*)d_in[23];
  const float* noise  = (const float*)d_in[24];

  float* ws = (float*)d_ws;
  const size_t NX  = (size_t)Bn * Sn * Dn;  // 3,276,800
  const size_t NXP = (size_t)Bn * Sn * G3;  // 9,830,400
  float* x       = ws;
  float* xp      = ws + NX;
  float* xnoisy  = xp;            // aliases xp[0, NX)    (dead between GRUs)
  float* aligned = xp + NX;       // aliases xp[NX, 2*NX)
  float* rnn     = ws + NX + NXP;
  float* wprev   = ws + 2 * NX + NXP;   // -> gen_x -> gen_rnn
  float* sa      = ws + 3 * NX + NXP;
  float* sb      = sa + 64;
  float* tsv     = sb + 64;
  uint*  Wf16    = (uint*)(tsv + 64);   // 98304 u32 (f16-packed Whh)

  float* out       = (float*)d_out;
  float* pred      = out;
  float* gpred     = out + 128;
  float* pn        = out + 256;
  float* out_noise = out + 256 + NX;

  const int ATTN_SMEM = (64 * 513 + 256 + 256 + 64 + 64 + 2) * 4;

  // 0. Whh -> f16 pairs
  k_w2f16<<<dim3(384), dim3(256), 0, stream>>>(Whh, Wf16, 98304);
  // 1. embedding sum
  k_embed_sum<<<dim3(Bn * Sn), dim3(Dn), 0, stream>>>(seqs, emb, x);
  // 2. xp = x @ Wih^T + bih
  k_gemm_abt<<<dim3(100, 6), dim3(256), 0, stream>>>(x, Wih, bih, xp, Bn * Sn, G3, Dn);
  // 3. rnn = GRU(xp)  — register-resident Whh
  k_gru_reg<<<dim3(Bn), dim3(512), 0, stream>>>(xp, Wf16, bhh, rnn);
  // 4. w_prev(full S) = rnn @ whk^T + b
  k_gemm_abt<<<dim3(100, 2), dim3(256), 0, stream>>>(rnn, whkW, whkb, wprev, Bn * Sn, Dn, Dn);
  // 5. fused attention + blend -> aligned  (parallel over s)
  k_attn_par<<<dim3(Bn, 7), dim3(256), ATTN_SMEM, stream>>>(x, wprev, w1W, w1b, w2W, w2b, aligned);
  // 6. diffusion scalars
  k_cumsetup<<<dim3(1), dim3(256), 0, stream>>>(betas, difft, tscale, sa, sb, tsv);
  // 7. x_noisy (into dead xp region)
  k_noisy<<<dim3(2048), dim3(256), 0, stream>>>(aligned, noise, sa, sb, xnoisy);
  // 8. predicted_noise (-> d_out) and gen_x (overwrites wprev)
  k_diff<<<dim3(4, 4, Bn), dim3(256), 0, stream>>>(Wd, xnoisy, tsv, aligned, noise, pn, wprev);
  // 9. gen xp = gen_x @ Wih^T + bih
  k_gemm_abt<<<dim3(100, 6), dim3(256), 0, stream>>>(wprev, Wih, bih, xp, Bn * Sn, G3, Dn);
  // 10. gen_rnn = GRU (overwrites gen_x slot)
  k_gru_reg<<<dim3(Bn), dim3(512), 0, stream>>>(xp, Wf16, bhh, wprev);
  // 11. pools
  k_pool<<<dim3(Bn), dim3(256), 0, stream>>>(rnn, wlW, wlb, outW, outb, pred);
  k_pool<<<dim3(Bn), dim3(256), 0, stream>>>(wprev, wlW, wlb, outW, outb, gpred);
  // 12. pass through normal_noise
  (void)hipMemcpyAsync(out_noise, noise, NX * sizeof(float), hipMemcpyDeviceToDevice, stream);
}

// Round 6
// 1366.986 us; speedup vs baseline: 7.2698x; 1.3135x over previous
//
#include <hip/hip_runtime.h>
#include <math.h>

// Problem constants
constexpr int Bn = 64, Sn = 200, Cn = 32, Dn = 256, Vn = 10000, Tn = 1000;
constexpr int G3 = 3 * Dn; // 768

typedef __fp16 h2_t __attribute__((ext_vector_type(2)));

static __device__ __forceinline__ h2_t as_h2(uint v) {
  union { uint u; h2_t h; } c; c.u = v; return c.h;
}
static __device__ __forceinline__ uint as_u32(h2_t h) {
  union { h2_t h; uint u; } c; c.h = h; return c.u;
}

// ---------------------------------------------------------------------------
// Whh f32 -> packed f16 pairs (u32), pair i = (w[2i], w[2i+1])
__global__ __launch_bounds__(256) void k_w2f16(const float* __restrict__ w,
    uint* __restrict__ o, int npairs) {
  int i = blockIdx.x * 256 + threadIdx.x;
  if (i < npairs) {
    h2_t pk = __builtin_amdgcn_cvt_pkrtz(w[2 * i], w[2 * i + 1]);
    o[i] = as_u32(pk);
  }
}

// ---------------------------------------------------------------------------
// x[b,s,d] = sum_c emb[seqs[b,s,c]][d]
__global__ __launch_bounds__(256) void k_embed_sum(const int* __restrict__ seqs,
    const float* __restrict__ emb, float* __restrict__ x) {
  const int bs = blockIdx.x;
  const int d = threadIdx.x;
  const int* row = seqs + (size_t)bs * Cn;
  float acc = 0.f;
#pragma unroll
  for (int c = 0; c < Cn; ++c) acc += emb[(size_t)row[c] * Dn + d];
  x[(size_t)bs * Dn + d] = acc;
}

// ---------------------------------------------------------------------------
// C[M,N] = A[M,K] @ B[N,K]^T + bias[N]   (row-major, K multiple of 16)
__global__ __launch_bounds__(256) void k_gemm_abt(const float* __restrict__ A,
    const float* __restrict__ Bm, const float* __restrict__ bias,
    float* __restrict__ Cm, int M, int N, int K) {
  __shared__ float As[16][132];
  __shared__ float Bs[16][132];
  const int m0 = blockIdx.x * 128, n0 = blockIdx.y * 128;
  const int tid = threadIdx.x;
  const int lk = tid & 15, lm = tid >> 4;
  const int tx = tid & 15, ty = tid >> 4;
  float acc[8][8] = {};
  for (int k0 = 0; k0 < K; k0 += 16) {
#pragma unroll
    for (int i = 0; i < 8; ++i) {
      int m = lm + i * 16;
      int gm = m0 + m, gn = n0 + m;
      As[lk][m] = (gm < M) ? A[(size_t)gm * K + k0 + lk] : 0.f;
      Bs[lk][m] = (gn < N) ? Bm[(size_t)gn * K + k0 + lk] : 0.f;
    }
    __syncthreads();
#pragma unroll
    for (int k = 0; k < 16; ++k) {
      float a[8], bb[8];
#pragma unroll
      for (int i = 0; i < 8; ++i) a[i] = As[k][ty * 8 + i];
#pragma unroll
      for (int j = 0; j < 8; ++j) bb[j] = Bs[k][tx * 8 + j];
#pragma unroll
      for (int i = 0; i < 8; ++i)
#pragma unroll
        for (int j = 0; j < 8; ++j) acc[i][j] += a[i] * bb[j];
    }
    __syncthreads();
  }
#pragma unroll
  for (int i = 0; i < 8; ++i) {
    int gm = m0 + ty * 8 + i;
    if (gm >= M) continue;
#pragma unroll
    for (int j = 0; j < 8; ++j) {
      int gn = n0 + tx * 8 + j;
      if (gn < N) Cm[(size_t)gm * N + gn] = acc[i][j] + bias[gn];
    }
  }
}

// ---------------------------------------------------------------------------
// GRU, register-resident f16 Whh, low-latency step. One block per batch.
// 512 threads: d = tid>>1 (output dim), half = tid&1 (k-half).
// Thread owns gate rows {d, D+d, 2D+d} over k in [128*half, 128*half+128)
// = 64 u32 per row = 192 u32 total, in arch VGPRs (launch_bounds(512,2)).
// Per step: 192 fdot2, ONE shfl_xor(1) reduce (adjacent lane), activation
// redundantly on both lanes (no divergence), one shfl_xor(2) to pack h pairs,
// double-buffered h in LDS -> ONE barrier per step.
__global__ __launch_bounds__(512, 2) void k_gru_reg2(const float* __restrict__ xp,
    const uint* __restrict__ Wh, const float* __restrict__ bhh,
    float* __restrict__ out) {
  const int b = blockIdx.x;
  const int tid = threadIdx.x;
  const int d = tid >> 1;      // 0..255
  const int half = tid & 1;    // k-half
  __shared__ uint h2s[2][128]; // h[256] as f16 pairs, double-buffered

  // one-time: weights into VGPRs (3 rows x 64 u32 = 192 regs)
  uint wr_[64], wz_[64], wn_[64];
  {
    const uint* base = Wh + 64 * half;
#pragma unroll
    for (int i = 0; i < 64; i += 4) {
      uint4 v;
      v = *reinterpret_cast<const uint4*>(base + (size_t)d * 128 + i);
      wr_[i] = v.x; wr_[i + 1] = v.y; wr_[i + 2] = v.z; wr_[i + 3] = v.w;
      v = *reinterpret_cast<const uint4*>(base + (size_t)(256 + d) * 128 + i);
      wz_[i] = v.x; wz_[i + 1] = v.y; wz_[i + 2] = v.z; wz_[i + 3] = v.w;
      v = *reinterpret_cast<const uint4*>(base + (size_t)(512 + d) * 128 + i);
      wn_[i] = v.x; wn_[i + 1] = v.y; wn_[i + 2] = v.z; wn_[i + 3] = v.w;
    }
  }
  const float* xpb = xp + (size_t)b * Sn * G3;
  const float b_r = bhh[d], b_z = bhh[256 + d], b_n = bhh[512 + d];
  float x_r = xpb[d], x_z = xpb[256 + d], x_n = xpb[512 + d];
  float h_old = 0.f;
  if (tid < 128) h2s[0][tid] = 0u;
  __syncthreads();

  for (int t = 0; t < Sn; ++t) {
    const int cur = t & 1;
    const uint* hp = &h2s[cur][64 * half];
    float ar = 0.f, az = 0.f, an = 0.f;
#pragma unroll
    for (int c = 0; c < 8; ++c) {
      uint4 v0 = *reinterpret_cast<const uint4*>(hp + 8 * c);
      uint4 v1 = *reinterpret_cast<const uint4*>(hp + 8 * c + 4);
      uint hh[8] = {v0.x, v0.y, v0.z, v0.w, v1.x, v1.y, v1.z, v1.w};
#pragma unroll
      for (int i = 0; i < 8; ++i) {
        h2_t hv = as_h2(hh[i]);
        ar = __builtin_amdgcn_fdot2(as_h2(wr_[8 * c + i]), hv, ar, false);
        az = __builtin_amdgcn_fdot2(as_h2(wz_[8 * c + i]), hv, az, false);
        an = __builtin_amdgcn_fdot2(as_h2(wn_[8 * c + i]), hv, an, false);
      }
    }
    // adjacent lane holds the other k-half (tid^1 = lane^1, same wave)
    ar += __shfl_xor(ar, 1);
    az += __shfl_xor(az, 1);
    an += __shfl_xor(an, 1);
    // both lanes compute the activation (redundant, divergence-free)
    float rv = 1.f / (1.f + __expf(-(x_r + ar + b_r)));
    float zv = 1.f / (1.f + __expf(-(x_z + az + b_z)));
    float nv = tanhf(x_n + rv * (an + b_n));
    float h = (1.f - zv) * nv + zv * h_old;
    h_old = h;
    if (half == 0) out[((size_t)b * Sn + t) * Dn + d] = h;
    if (t + 1 < Sn) {  // prefetch next step's xp triple (both lanes)
      const float* xr = xpb + (size_t)(t + 1) * G3;
      x_r = xr[d]; x_z = xr[256 + d]; x_n = xr[512 + d];
    }
    // pack (h[2i], h[2i+1]): lane 4i takes partner h from lane 4i+2
    float hp2 = __shfl_xor(h, 2);
    if ((tid & 3) == 0) h2s[cur ^ 1][tid >> 2] = as_u32(__builtin_amdgcn_cvt_pkrtz(h, hp2));
    __syncthreads();
  }
}

// ---------------------------------------------------------------------------
// Parallel location-attention + blend. softmax is over the 2-class axis, so
// every (b,s) is independent. Grid (B, 7): block stages w1 in dynamic LDS
// once, then handles 29 s-values. aligned[b,0,:]=x[b,0,:].
__global__ __launch_bounds__(256) void k_attn_par(const float* __restrict__ x,
    const float* __restrict__ wprev, const float* __restrict__ w1W,
    const float* __restrict__ w1b, const float* __restrict__ w2W,
    const float* __restrict__ w2b, float* __restrict__ aligned) {
  extern __shared__ float sm[];
  float* w1s = sm;                  // 64 x 513 (pad: conflict-free)
  float* ek  = w1s + 64 * 513;      // 256
  float* wp  = ek + 256;            // 256
  float* eks = wp + 256;            // 64
  float* t1  = eks + 64;            // 64
  float* a01 = t1 + 64;             // 2
  const int b = blockIdx.x, cy = blockIdx.y, tid = threadIdx.x;
  for (int idx = tid; idx < 64 * 512; idx += 256) {
    int f = idx >> 9, c = idx & 511;
    w1s[f * 513 + c] = w1W[idx];
  }
  ek[tid] = x[(size_t)b * Sn * Dn + tid];
  __syncthreads();
  const int f = tid >> 2, kq = tid & 3;
  {
    float p = 0.f;
    const float* wr = w1s + f * 513;
#pragma unroll 8
    for (int j = 0; j < 64; ++j) {
      int k = 64 * kq + ((j + 16 * kq) & 63);  // stagger: spread banks
      p += ek[k] * wr[k];
    }
    p += __shfl_xor(p, 1);
    p += __shfl_xor(p, 2);
    if (kq == 0) eks[f] = p + w1b[f];
  }
  if (cy == 0) aligned[(size_t)b * Sn * Dn + tid] = ek[tid];
  __syncthreads();
  const int s0 = 1 + cy * 29;
  const int s1 = (s0 + 29 < Sn) ? s0 + 29 : Sn;
  for (int s = s0; s < s1; ++s) {
    wp[tid] = wprev[((size_t)b * Sn + (s - 1)) * Dn + tid];
    __syncthreads();
    float p = 0.f;
    const float* wr = w1s + f * 513 + 256;
#pragma unroll 8
    for (int j = 0; j < 64; ++j) {
      int k = 64 * kq + ((j + 16 * kq) & 63);
      p += wp[k] * wr[k];
    }
    p += __shfl_xor(p, 1);
    p += __shfl_xor(p, 2);
    if (kq == 0) t1[f] = tanhf(eks[f] + p);
    __syncthreads();
    if (tid == 0) {
      float l0 = w2b[0], l1 = w2b[1];
#pragma unroll
      for (int j = 0; j < 64; ++j) { l0 += t1[j] * w2W[j]; l1 += t1[j] * w2W[64 + j]; }
      float m = fmaxf(l0, l1);
      float e0 = __expf(l0 - m), e1 = __expf(l1 - m);
      float inv = 1.f / (e0 + e1);
      a01[0] = e0 * inv; a01[1] = e1 * inv;
    }
    __syncthreads();
    aligned[((size_t)b * Sn + s) * Dn + tid] = ek[tid] * a01[0] + wp[tid] * a01[1];
    __syncthreads();
  }
}

// ---------------------------------------------------------------------------
// cumprod(1-betas) -> per-batch sqrt(alpha), sqrt(1-alpha), time_scale gather
__global__ __launch_bounds__(256) void k_cumsetup(const float* __restrict__ betas,
    const int* __restrict__ difft, const float* __restrict__ tscale,
    float* __restrict__ sa, float* __restrict__ sb, float* __restrict__ tsv) {
  __shared__ float bl[Tn];
  const int tid = threadIdx.x;
  for (int i = tid; i < Tn; i += 256) bl[i] = betas[i];
  __syncthreads();
  if (tid == 0) {
    float p = 1.f;
    for (int t = 0; t < Tn; ++t) { p *= (1.f - bl[t]); bl[t] = p; }
  }
  __syncthreads();
  if (tid < Bn) {
    int tb = difft[tid];
    float a = bl[tb];
    sa[tid] = sqrtf(a);
    sb[tid] = sqrtf(1.f - a);
    tsv[tid] = tscale[tb];
  }
}

// ---------------------------------------------------------------------------
// x_noisy = aligned*sqrt(alpha[b]) + noise*sqrt(1-alpha[b])
__global__ __launch_bounds__(256) void k_noisy(const float* __restrict__ aligned,
    const float* __restrict__ noise, const float* __restrict__ sa,
    const float* __restrict__ sb, float* __restrict__ xn) {
  const size_t NT = (size_t)Bn * Sn * Dn;
  const size_t stride = (size_t)gridDim.x * blockDim.x;
  for (size_t i = (size_t)blockIdx.x * blockDim.x + threadIdx.x; i < NT; i += stride) {
    int b = (int)(i / (Sn * Dn));
    xn[i] = aligned[i] * sa[b] + noise[i] * sb[b];
  }
}

// ---------------------------------------------------------------------------
// pn[b,c,d] = ts[b] * sum_s Wd[c,s]*xn[b,s,d];  genx = aligned + noise - pn
__global__ __launch_bounds__(256) void k_diff(const float* __restrict__ Wd,
    const float* __restrict__ Xn, const float* __restrict__ tsv,
    const float* __restrict__ aligned, const float* __restrict__ noise,
    float* __restrict__ pn, float* __restrict__ genx) {
  const int bz = blockIdx.z;
  const float* Bm = Xn + (size_t)bz * Sn * Dn;
  __shared__ float As[16][65];
  __shared__ float Bs[16][65];
  const int m0 = blockIdx.x * 64, n0 = blockIdx.y * 64;
  const int tid = threadIdx.x;
  const int lk = tid & 15, lm = tid >> 4;
  const int ln = tid & 63, lq = tid >> 6;
  const int tx = tid & 15, ty = tid >> 4;
  float acc[4][4] = {};
  for (int k0 = 0; k0 < Sn; k0 += 16) {
#pragma unroll
    for (int i = 0; i < 4; ++i) {
      int m = lm + i * 16;
      As[lk][m] = (m0 + m < Sn && k0 + lk < Sn) ? Wd[(size_t)(m0 + m) * Sn + k0 + lk] : 0.f;
    }
#pragma unroll
    for (int i = 0; i < 4; ++i) {
      int k = lq + i * 4;
      Bs[k][ln] = (k0 + k < Sn) ? Bm[(size_t)(k0 + k) * Dn + n0 + ln] : 0.f;
    }
    __syncthreads();
#pragma unroll
    for (int k = 0; k < 16; ++k) {
      float a[4], bb[4];
#pragma unroll
      for (int i = 0; i < 4; ++i) a[i] = As[k][ty * 4 + i];
#pragma unroll
      for (int j = 0; j < 4; ++j) bb[j] = Bs[k][tx * 4 + j];
#pragma unroll
      for (int i = 0; i < 4; ++i)
#pragma unroll
        for (int j = 0; j < 4; ++j) acc[i][j] += a[i] * bb[j];
    }
    __syncthreads();
  }
  const float ts = tsv[bz];
#pragma unroll
  for (int i = 0; i < 4; ++i) {
    int c = m0 + ty * 4 + i;
    if (c >= Sn) continue;
#pragma unroll
    for (int j = 0; j < 4; ++j) {
      int dd = n0 + tx * 4 + j;
      size_t idx = ((size_t)bz * Sn + c) * Dn + dd;
      float val = acc[i][j] * ts;
      pn[idx] = val;
      genx[idx] = aligned[idx] + noise[idx] - val;
    }
  }
}

// ---------------------------------------------------------------------------
// attention pool: att=softmax(rnn@wl+b over s); feat=sum att*rnn; pred=feat@outW^T+b
__global__ __launch_bounds__(256) void k_pool(const float* __restrict__ rnn,
    const float* __restrict__ wlW, const float* __restrict__ wlb,
    const float* __restrict__ outW, const float* __restrict__ outb,
    float* __restrict__ out2) {
  const int b = blockIdx.x, tid = threadIdx.x;
  __shared__ float wl[Dn], att[256], red[256], feat[Dn];
  wl[tid] = wlW[tid];
  __syncthreads();
  float wv = -1e30f;
  if (tid < Sn) {
    const float* r = rnn + ((size_t)b * Sn + tid) * Dn;
    float a = wlb[0];
    for (int k = 0; k < Dn; ++k) a += r[k] * wl[k];
    wv = a;
  }
  red[tid] = wv;
  __syncthreads();
  for (int off = 128; off > 0; off >>= 1) {
    if (tid < off) red[tid] = fmaxf(red[tid], red[tid + off]);
    __syncthreads();
  }
  const float m = red[0];
  __syncthreads();
  float e = (tid < Sn) ? __expf(wv - m) : 0.f;
  red[tid] = e;
  __syncthreads();
  for (int off = 128; off > 0; off >>= 1) {
    if (tid < off) red[tid] += red[tid + off];
    __syncthreads();
  }
  const float inv = 1.f / red[0];
  att[tid] = e * inv;
  __syncthreads();
  const float* rb = rnn + (size_t)b * Sn * Dn;
  float a = 0.f;
  for (int s = 0; s < Sn; ++s) a += rb[(size_t)s * Dn + tid] * att[s];
  feat[tid] = a;
  __syncthreads();
  if (tid < 2) {
    float acc = outb[tid];
    for (int k = 0; k < Dn; ++k) acc += feat[k] * outW[tid * Dn + k];
    out2[b * 2 + tid] = acc;
  }
}

// ---------------------------------------------------------------------------
extern "C" void kernel_launch(void* const* d_in, const int* in_sizes, int n_in,
                              void* d_out, int out_size, void* d_ws, size_t ws_size,
                              hipStream_t stream) {
  const int*   seqs   = (const int*)  d_in[0];
  const int*   difft  = (const int*)  d_in[5];
  const float* emb    = (const float*)d_in[6];
  const float* Wih    = (const float*)d_in[7];
  const float* Whh    = (const float*)d_in[8];
  const float* bih    = (const float*)d_in[9];
  const float* bhh    = (const float*)d_in[10];
  const float* whkW   = (const float*)d_in[11];
  const float* whkb   = (const float*)d_in[12];
  const float* w1W    = (const float*)d_in[13];
  const float* w1b    = (const float*)d_in[14];
  const float* w2W    = (const float*)d_in[15];
  const float* w2b    = (const float*)d_in[16];
  const float* wlW    = (const float*)d_in[17];
  const float* wlb    = (const float*)d_in[18];
  const float* outW   = (const float*)d_in[19];
  const float* outb   = (const float*)d_in[20];
  const float* betas  = (const float*)d_in[21];
  const float* Wd     = (const float*)d_in[22];
  const float* tscale = (const float*)d_in[23];
  const float* noise  = (const float*)d_in[24];

  float* ws = (float*)d_ws;
  const size_t NX  = (size_t)Bn * Sn * Dn;  // 3,276,800
  const size_t NXP = (size_t)Bn * Sn * G3;  // 9,830,400
  float* x       = ws;
  float* xp      = ws + NX;
  float* xnoisy  = xp;            // aliases xp[0, NX)    (dead between GRUs)
  float* aligned = xp + NX;       // aliases xp[NX, 2*NX)
  float* rnn     = ws + NX + NXP;
  float* wprev   = ws + 2 * NX + NXP;   // -> gen_x -> gen_rnn
  float* sa      = ws + 3 * NX + NXP;
  float* sb      = sa + 64;
  float* tsv     = sb + 64;
  uint*  Wf16    = (uint*)(tsv + 64);   // 98304 u32 (f16-packed Whh)

  float* out       = (float*)d_out;
  float* pred      = out;
  float* gpred     = out + 128;
  float* pn        = out + 256;
  float* out_noise = out + 256 + NX;

  const int ATTN_SMEM = (64 * 513 + 256 + 256 + 64 + 64 + 2) * 4;

  // 0. Whh -> f16 pairs
  k_w2f16<<<dim3(384), dim3(256), 0, stream>>>(Whh, Wf16, 98304);
  // 1. embedding sum
  k_embed_sum<<<dim3(Bn * Sn), dim3(Dn), 0, stream>>>(seqs, emb, x);
  // 2. xp = x @ Wih^T + bih
  k_gemm_abt<<<dim3(100, 6), dim3(256), 0, stream>>>(x, Wih, bih, xp, Bn * Sn, G3, Dn);
  // 3. rnn = GRU(xp)  — register-resident Whh, 1 barrier/step
  k_gru_reg2<<<dim3(Bn), dim3(512), 0, stream>>>(xp, Wf16, bhh, rnn);
  // 4. w_prev(full S) = rnn @ whk^T + b
  k_gemm_abt<<<dim3(100, 2), dim3(256), 0, stream>>>(rnn, whkW, whkb, wprev, Bn * Sn, Dn, Dn);
  // 5. fused attention + blend -> aligned  (parallel over s)
  k_attn_par<<<dim3(Bn, 7), dim3(256), ATTN_SMEM, stream>>>(x, wprev, w1W, w1b, w2W, w2b, aligned);
  // 6. diffusion scalars
  k_cumsetup<<<dim3(1), dim3(256), 0, stream>>>(betas, difft, tscale, sa, sb, tsv);
  // 7. x_noisy (into dead xp region)
  k_noisy<<<dim3(2048), dim3(256), 0, stream>>>(aligned, noise, sa, sb, xnoisy);
  // 8. predicted_noise (-> d_out) and gen_x (overwrites wprev)
  k_diff<<<dim3(4, 4, Bn), dim3(256), 0, stream>>>(Wd, xnoisy, tsv, aligned, noise, pn, wprev);
  // 9. gen xp = gen_x @ Wih^T + bih
  k_gemm_abt<<<dim3(100, 6), dim3(256), 0, stream>>>(wprev, Wih, bih, xp, Bn * Sn, G3, Dn);
  // 10. gen_rnn = GRU (overwrites gen_x slot)
  k_gru_reg2<<<dim3(Bn), dim3(512), 0, stream>>>(xp, Wf16, bhh, wprev);
  // 11. pools
  k_pool<<<dim3(Bn), dim3(256), 0, stream>>>(rnn, wlW, wlb, outW, outb, pred);
  k_pool<<<dim3(Bn), dim3(256), 0, stream>>>(wprev, wlW, wlb, outW, outb, gpred);
  // 12. pass through normal_noise
  (void)hipMemcpyAsync(out_noise, noise, NX * sizeof(float), hipMemcpyDeviceToDevice, stream);
}